// Round 1
// baseline (22732.385 us; speedup 1.0000x reference)
//
#include <hip/hip_runtime.h>
#include <hip/hip_cooperative_groups.h>
#include <cmath>

namespace cg = cooperative_groups;

// Problem constants
#define MB_ 8192      // B*T tokens
// H = 512, S = 320, K = 1024, NQ = 4

// ---------------- generic 64x64 tile f32 GEMM ----------------
// BT=true : C[m][n] = sum_k A[m][k] * B[n][k]   (B is N x K row-major)
// BT=false: C[m][n] = sum_k A[m][k] * B[k][n]   (B is K x N row-major)
template<bool BT>
__global__ __launch_bounds__(256)
void gemm64(const float* __restrict__ A, const float* __restrict__ B,
            float* __restrict__ C, int M, int N, int K,
            const float* __restrict__ bias1, const float* __restrict__ bias2)
{
    __shared__ float Al[32][68];   // [k][m], stride 68 keeps float4 reads 16B-aligned
    __shared__ float Bl[32][68];   // [k][n]
    const int m0 = blockIdx.y * 64, n0 = blockIdx.x * 64;
    const int t = threadIdx.x;
    const int tm = t >> 4, tn = t & 15;   // 16x16 threads, 4x4 micro-tile
    float acc[4][4] = {{0.f, 0.f, 0.f, 0.f}};

    for (int k0 = 0; k0 < K; k0 += 32) {
        #pragma unroll
        for (int i = 0; i < 2; i++) {
            int f4 = t + i * 256;            // 512 float4 = 64 rows x 8
            int row = f4 >> 3, c4 = f4 & 7;
            float4 v = *(const float4*)(A + (size_t)(m0 + row) * K + k0 + c4 * 4);
            Al[c4*4+0][row] = v.x; Al[c4*4+1][row] = v.y;
            Al[c4*4+2][row] = v.z; Al[c4*4+3][row] = v.w;
        }
        if (BT) {
            #pragma unroll
            for (int i = 0; i < 2; i++) {
                int f4 = t + i * 256;
                int row = f4 >> 3, c4 = f4 & 7;   // row = n index
                float4 v = *(const float4*)(B + (size_t)(n0 + row) * K + k0 + c4 * 4);
                Bl[c4*4+0][row] = v.x; Bl[c4*4+1][row] = v.y;
                Bl[c4*4+2][row] = v.z; Bl[c4*4+3][row] = v.w;
            }
        } else {
            #pragma unroll
            for (int i = 0; i < 2; i++) {
                int f4 = t + i * 256;
                int kk = f4 >> 4, c4 = f4 & 15;   // 32 rows x 16 float4
                float4 v = *(const float4*)(B + (size_t)(k0 + kk) * N + n0 + c4 * 4);
                *(float4*)&Bl[kk][c4 * 4] = v;
            }
        }
        __syncthreads();
        #pragma unroll
        for (int k = 0; k < 32; k++) {
            float4 a4 = *(const float4*)&Al[k][tm * 4];
            float4 b4 = *(const float4*)&Bl[k][tn * 4];
            float av[4] = {a4.x, a4.y, a4.z, a4.w};
            float bv[4] = {b4.x, b4.y, b4.z, b4.w};
            #pragma unroll
            for (int i = 0; i < 4; i++)
                #pragma unroll
                for (int j = 0; j < 4; j++)
                    acc[i][j] = fmaf(av[i], bv[j], acc[i][j]);
        }
        __syncthreads();
    }
    float bn[4];
    #pragma unroll
    for (int j = 0; j < 4; j++) {
        float bb = 0.f;
        if (bias1) bb += bias1[n0 + tn * 4 + j];
        if (bias2) bb += bias2[n0 + tn * 4 + j];
        bn[j] = bb;
    }
    #pragma unroll
    for (int i = 0; i < 4; i++) {
        float4 o;
        o.x = acc[i][0] + bn[0]; o.y = acc[i][1] + bn[1];
        o.z = acc[i][2] + bn[2]; o.w = acc[i][3] + bn[3];
        *(float4*)(C + (size_t)(m0 + tm * 4 + i) * N + n0 + tn * 4) = o;
    }
}

// ---------------- LayerNorm + ReLU in place, one block per token row ----------------
__global__ __launch_bounds__(256)
void ln_relu_kernel(float* __restrict__ X, const float* __restrict__ g,
                    const float* __restrict__ bb)
{
    __shared__ float red[256];
    __shared__ float stat[2];
    const int row = blockIdx.x, t = threadIdx.x;
    float x0 = X[(size_t)row * 512 + t];
    float x1 = X[(size_t)row * 512 + 256 + t];
    red[t] = x0 + x1;
    __syncthreads();
    for (int o = 128; o > 0; o >>= 1) { if (t < o) red[t] += red[t + o]; __syncthreads(); }
    if (t == 0) stat[0] = red[0] * (1.f / 512.f);
    __syncthreads();
    float mu = stat[0];
    float d0 = x0 - mu, d1 = x1 - mu;
    red[t] = d0 * d0 + d1 * d1;
    __syncthreads();
    for (int o = 128; o > 0; o >>= 1) { if (t < o) red[t] += red[t + o]; __syncthreads(); }
    if (t == 0) stat[1] = red[0] * (1.f / 512.f);
    __syncthreads();
    float rs = rsqrtf(stat[1] + 1e-5f);
    float y0 = d0 * rs * g[t] + bb[t];
    float y1 = d1 * rs * g[256 + t] + bb[256 + t];
    X[(size_t)row * 512 + t] = fmaxf(y0, 0.f);
    X[(size_t)row * 512 + 256 + t] = fmaxf(y1, 0.f);
}

// ---------------- row squared-norms (codebooks: 4096 rows x 512) ----------------
__global__ __launch_bounds__(256)
void rownorm_kernel(const float* __restrict__ Ein, float* __restrict__ norms)
{
    __shared__ float red[256];
    const int row = blockIdx.x, t = threadIdx.x;
    float a = Ein[(size_t)row * 512 + t];
    float b = Ein[(size_t)row * 512 + 256 + t];
    red[t] = a * a + b * b;
    __syncthreads();
    for (int o = 128; o > 0; o >>= 1) { if (t < o) red[t] += red[t + o]; __syncthreads(); }
    if (t == 0) norms[row] = red[0];
}

// ---------------- VQ argmin + STE update, one block per token ----------------
__global__ __launch_bounds__(256)
void vq_update_kernel(const float* __restrict__ D, const float* __restrict__ norms,
                      const float* __restrict__ cb, float* __restrict__ residual,
                      float* __restrict__ quant, float* __restrict__ loss_acc)
{
    __shared__ unsigned long long red[256];
    __shared__ float fred[256];
    __shared__ int sidx;
    __shared__ float sdmin;
    const int tok = blockIdx.x, t = threadIdx.x;
    // argmin over k of (||E_k||^2 - 2 r.E_k); ||r||^2 is a constant shift.
    unsigned long long best = ~0ull;
    #pragma unroll
    for (int i = 0; i < 4; i++) {
        int k = t + i * 256;
        float d = fmaf(-2.f, D[(size_t)tok * 1024 + k], norms[k]);
        unsigned u = __float_as_uint(d);
        u = (u & 0x80000000u) ? ~u : (u | 0x80000000u);  // order-preserving map
        unsigned long long p = ((unsigned long long)u << 32) | (unsigned)k;
        best = p < best ? p : best;                      // min value, then min index
    }
    red[t] = best;
    __syncthreads();
    for (int o = 128; o > 0; o >>= 1) {
        if (t < o) red[t] = red[t + o] < red[t] ? red[t + o] : red[t];
        __syncthreads();
    }
    if (t == 0) {
        unsigned long long r0 = red[0];
        sidx = (int)(r0 & 0xffffffffu);
        unsigned uv = (unsigned)(r0 >> 32);
        unsigned orig = (uv & 0x80000000u) ? (uv ^ 0x80000000u) : ~uv;
        sdmin = __uint_as_float(orig);
    }
    float r0v = residual[(size_t)tok * 512 + t];
    float r1v = residual[(size_t)tok * 512 + 256 + t];
    fred[t] = r0v * r0v + r1v * r1v;
    __syncthreads();
    for (int o = 128; o > 0; o >>= 1) { if (t < o) fred[t] += fred[t + o]; __syncthreads(); }
    int idx = sidx;
    if (t == 0) atomicAdd(loss_acc, sdmin + fred[0]);   // ||E-r||^2 summed over token
    const float* E = cb + (size_t)idx * 512;
    float e0 = E[t], e1 = E[256 + t];
    // replicate reference STE rounding exactly: q_st = r + (quantized - r)
    float q0 = r0v + (e0 - r0v);
    float q1 = r1v + (e1 - r1v);
    residual[(size_t)tok * 512 + t]       = r0v - q0;
    residual[(size_t)tok * 512 + 256 + t] = r1v - q1;
    quant[(size_t)tok * 512 + t]       += q0;
    quant[(size_t)tok * 512 + 256 + t] += q1;
}

// ---------------- persistent cooperative LSTM layer ----------------
// 128 blocks x 256 threads. Block owns 4 hidden units j=bid*4..bid*4+3 -> 16 gate cols.
// Dot phase: thread (cl = t&15, ks = t>>4): gate column cl, K-slice ks*32..+31 held in regs.
__global__ __launch_bounds__(256)
void lstm_layer_kernel(const float* __restrict__ P, const float* __restrict__ wh,
                       float* __restrict__ Hs, float* __restrict__ h0buf,
                       float* __restrict__ h1buf)
{
    cg::grid_group grid = cg::this_grid();
    __shared__ float hl[16 * 512];     // h staged per step (b-major)
    __shared__ float part[16 * 256];   // [ks][cl*16 + b]
    __shared__ float gl[256];          // gates [cl*16 + b]
    __shared__ float c_lds[64];        // cell state, block-owned slice
    const int t = threadIdx.x, bid = blockIdx.x;
    const int cl = t & 15, ks = t >> 4;
    const int gate = cl >> 2, jj = cl & 3;
    const int j_base = bid * 4;
    float wr[32];
    {
        const float* wrow = wh + (size_t)(gate * 512 + j_base + jj) * 512 + ks * 32;
        #pragma unroll
        for (int i = 0; i < 32; i++) wr[i] = wrow[i];
    }
    if (t < 64) {
        c_lds[t] = 0.f;
        int b = t >> 2;
        h0buf[b * 512 + j_base + (t & 3)] = 0.f;
    }
    const int cl_r = t >> 4, b_r = t & 15;           // reduction-phase mapping
    const int gate_r = cl_r >> 2, jj_r = cl_r & 3;
    grid.sync();
    for (int step = 0; step < 512; step++) {
        const float* hin = (step & 1) ? h1buf : h0buf;
        float* hout = (step & 1) ? h0buf : h1buf;
        for (int i = t; i < 2048; i += 256)
            ((float4*)hl)[i] = ((const float4*)hin)[i];
        float pv = P[(size_t)(b_r * 512 + step) * 2048 + gate_r * 512 + j_base + jj_r];
        __syncthreads();
        float accb[16];
        #pragma unroll
        for (int b = 0; b < 16; b++) {
            const float4* hb = (const float4*)(hl + b * 512 + ks * 32);
            float a0 = 0.f, a1 = 0.f, a2 = 0.f, a3 = 0.f;
            #pragma unroll
            for (int k4 = 0; k4 < 8; k4++) {
                float4 h4 = hb[k4];
                a0 = fmaf(h4.x, wr[k4 * 4 + 0], a0);
                a1 = fmaf(h4.y, wr[k4 * 4 + 1], a1);
                a2 = fmaf(h4.z, wr[k4 * 4 + 2], a2);
                a3 = fmaf(h4.w, wr[k4 * 4 + 3], a3);
            }
            accb[b] = (a0 + a1) + (a2 + a3);
        }
        #pragma unroll
        for (int b = 0; b < 16; b++)
            part[ks * 256 + cl * 16 + b] = accb[b];
        __syncthreads();
        float gv = pv;
        #pragma unroll
        for (int k = 0; k < 16; k++)
            gv += part[k * 256 + cl_r * 16 + b_r];
        gl[cl_r * 16 + b_r] = gv;
        __syncthreads();
        if (t < 64) {
            int b = t >> 2, jr = t & 3;
            float iv = gl[(0 + jr) * 16 + b];
            float fv = gl[(4 + jr) * 16 + b];
            float gg = gl[(8 + jr) * 16 + b];
            float ov = gl[(12 + jr) * 16 + b];
            float ig = 1.f / (1.f + expf(-iv));
            float fg = 1.f / (1.f + expf(-fv));
            float og = 1.f / (1.f + expf(-ov));
            float cn = fg * c_lds[t] + ig * tanhf(gg);
            float hn = og * tanhf(cn);
            c_lds[t] = cn;
            int j = j_base + jr;
            hout[b * 512 + j] = hn;
            Hs[(size_t)(b * 512 + step) * 512 + j] = hn;
        }
        grid.sync();
    }
}

__global__ void finalize_loss_kernel(const float* __restrict__ acc, float* __restrict__ out)
{
    int q = threadIdx.x;
    if (q < 4) out[2621440 + q] = acc[q] * (1.f / 4194304.f);  // mean over B*T*H
}

extern "C" void kernel_launch(void* const* d_in, const int* in_sizes, int n_in,
                              void* d_out, int out_size, void* d_ws, size_t ws_size,
                              hipStream_t stream)
{
    const float* waveform  = (const float*)d_in[0];
    const float* enc_w     = (const float*)d_in[1];
    const float* enc_b     = (const float*)d_in[2];
    const float* ln_g      = (const float*)d_in[3];
    const float* ln_b      = (const float*)d_in[4];
    const float* codebooks = (const float*)d_in[5];
    const float* lstm_wi   = (const float*)d_in[6];
    const float* lstm_wh   = (const float*)d_in[7];
    const float* lstm_bi   = (const float*)d_in[8];
    const float* lstm_bh   = (const float*)d_in[9];
    const float* dec_w     = (const float*)d_in[10];
    const float* dec_b     = (const float*)d_in[11];
    float* out = (float*)d_out;

    float* ws = (float*)d_ws;                  // layout in floats
    float* residual = ws;                      // 4,194,304
    float* quant    = ws + 4194304;            // 4,194,304
    float* H1       = ws + 8388608;            // 4,194,304
    float* H2       = ws + 12582912;           // 4,194,304
    float* big      = ws + 16777216;           // 16,777,216 (VQ distances D, then LSTM P)
    float* hb0      = ws + 33554432;           // 8192
    float* hb1      = ws + 33562624;           // 8192
    float* norms    = ws + 33570816;           // 4096
    float* loss_acc = ws + 33574912;           // 4

    hipMemsetAsync(quant, 0, (size_t)4194304 * sizeof(float), stream);
    hipMemsetAsync(loss_acc, 0, 4 * sizeof(float), stream);

    // Encoder: (8192x320)@(320x512)+b -> residual; then LN+ReLU in place
    gemm64<false><<<dim3(8, 128), 256, 0, stream>>>(waveform, enc_w, residual,
                                                    8192, 512, 320, enc_b, nullptr);
    ln_relu_kernel<<<8192, 256, 0, stream>>>(residual, ln_g, ln_b);

    // VQ
    rownorm_kernel<<<4096, 256, 0, stream>>>(codebooks, norms);
    for (int q = 0; q < 4; q++) {
        const float* cb = codebooks + (size_t)q * 1024 * 512;
        gemm64<true><<<dim3(16, 128), 256, 0, stream>>>(residual, cb, big,
                                                        8192, 1024, 512, nullptr, nullptr);
        vq_update_kernel<<<8192, 256, 0, stream>>>(big, norms + q * 1024, cb,
                                                   residual, quant, loss_acc + q);
    }

    // LSTM layer 1: P = quant@wi1^T + bi1 + bh1, then recurrence
    gemm64<true><<<dim3(32, 128), 256, 0, stream>>>(quant, lstm_wi, big,
                                                    8192, 2048, 512, lstm_bi, lstm_bh);
    {
        const float* Pp = big; const float* whp = lstm_wh;
        float* Hsp = H1; float* h0p = hb0; float* h1p = hb1;
        void* args[] = {&Pp, &whp, &Hsp, &h0p, &h1p};
        hipLaunchCooperativeKernel((void*)lstm_layer_kernel, dim3(128), dim3(256),
                                   args, 0, stream);
    }
    // LSTM layer 2
    gemm64<true><<<dim3(32, 128), 256, 0, stream>>>(H1, lstm_wi + (size_t)2048 * 512, big,
                                                    8192, 2048, 512, lstm_bi + 2048, lstm_bh + 2048);
    {
        const float* Pp = big; const float* whp = lstm_wh + (size_t)2048 * 512;
        float* Hsp = H2; float* h0p = hb0; float* h1p = hb1;
        void* args[] = {&Pp, &whp, &Hsp, &h0p, &h1p};
        hipLaunchCooperativeKernel((void*)lstm_layer_kernel, dim3(128), dim3(256),
                                   args, 0, stream);
    }
    // Decoder: (8192x512)@(512x320)+b -> d_out (reshape is layout-identity)
    gemm64<false><<<dim3(5, 128), 256, 0, stream>>>(H2, dec_w, out,
                                                    8192, 320, 512, dec_b, nullptr);
    finalize_loss_kernel<<<1, 4, 0, stream>>>(loss_acc, out);
}